// Round 1
// baseline (92.860 us; speedup 1.0000x reference)
//
#include <hip/hip_runtime.h>
#include <hip/hip_bf16.h>

typedef __attribute__((ext_vector_type(8))) short short8;
typedef __attribute__((ext_vector_type(4))) float f32x4;

static constexpr int S_ = 256;
static constexpr int D_ = 64;
static constexpr int QB = 4;
// softmax scale * log2(e): GEMM then directly produces log2-domain scores
static constexpr float QSCALE = 0.125f * 1.44269504088896340736f;

__device__ __forceinline__ float bf2f(short b) {
    union { unsigned int u; float f; } x;
    x.u = ((unsigned int)(unsigned short)b) << 16;
    return x.f;
}
__device__ __forceinline__ unsigned short f2bf(float f) {
    union { float f; unsigned int u; } x; x.f = f;
    unsigned int u = x.u + 0x7fffu + ((x.u >> 16) & 1u);   // RNE
    return (unsigned short)(u >> 16);
}

__global__ __launch_bounds__(256, 2) void tritt_fused(
    const float* __restrict__ qg, const float* __restrict__ k1g,
    const float* __restrict__ k2g, const float* __restrict__ v1g,
    const float* __restrict__ v2g, float* __restrict__ outg)
{
    __shared__ unsigned short sK1[S_ * D_];   // bf16, XOR-swizzled rows
    __shared__ unsigned short sK2[S_ * D_];
    __shared__ float sQ[QB * D_];             // pre-scaled Q
    __shared__ float sPi[QB][S_];
    __shared__ float sPj[QB][S_];
    __shared__ float sTmp[4][S_];             // pj wave-partials, then O partials
    __shared__ float sL[QB];

    const int tid = threadIdx.x;
    const int h  = blockIdx.x >> 6;
    const int q0 = (blockIdx.x & 63) * QB;

    const float* K1h = k1g + h * (S_ * D_);
    const float* K2h = k2g + h * (S_ * D_);

    // ---- stage K1,K2 as swizzled bf16 ----
    #pragma unroll
    for (int it = 0; it < 16; ++it) {
        const int e4  = tid * 4 + it * 1024;
        const int row = e4 >> 6, d = e4 & 63;
        const int idx = row * 64 + (d ^ ((row & 7) << 3));
        const float4 a = *(const float4*)(K1h + e4);
        sK1[idx]   = f2bf(a.x); sK1[idx+1] = f2bf(a.y);
        sK1[idx+2] = f2bf(a.z); sK1[idx+3] = f2bf(a.w);
        const float4 b = *(const float4*)(K2h + e4);
        sK2[idx]   = f2bf(b.x); sK2[idx+1] = f2bf(b.y);
        sK2[idx+2] = f2bf(b.z); sK2[idx+3] = f2bf(b.w);
    }
    sQ[tid] = qg[(h * S_ + q0 + (tid >> 6)) * D_ + (tid & 63)] * QSCALE;
    __syncthreads();

    const int w   = tid >> 6;   // wave id -> i-strip [w*64, w*64+64)
    const int l   = tid & 63;
    const int g   = l >> 4;     // 16-lane group (holds k-slice g*8..g*8+7)
    const int sub = l & 15;

    for (int qq = 0; qq < QB; ++qq) {
        // ---- A fragments: W[i,d] = K1[i,d] * Qs[d], bf16, in registers ----
        float qs[2][8];
        #pragma unroll
        for (int k = 0; k < 2; ++k) {
            const f32x4 a = *(const f32x4*)&sQ[qq * 64 + k * 32 + g * 8];
            const f32x4 b = *(const f32x4*)&sQ[qq * 64 + k * 32 + g * 8 + 4];
            qs[k][0]=a[0]; qs[k][1]=a[1]; qs[k][2]=a[2]; qs[k][3]=a[3];
            qs[k][4]=b[0]; qs[k][5]=b[1]; qs[k][6]=b[2]; qs[k][7]=b[3];
        }
        short8 afrag[4][2];
        #pragma unroll
        for (int it = 0; it < 4; ++it) {
            const int row = w * 64 + it * 16 + sub;
            const int sw  = (row & 7) << 3;
            #pragma unroll
            for (int k = 0; k < 2; ++k) {
                const short8 kf = *(const short8*)&sK1[row * 64 + ((k * 32 + g * 8) ^ sw)];
                short8 af;
                #pragma unroll
                for (int e = 0; e < 8; ++e)
                    af[e] = (short)f2bf(bf2f(kf[e]) * qs[k][e]);
                afrag[it][k] = af;
            }
        }

        float pireg[4][4];
        float pjreg[16];
        #pragma unroll
        for (int a = 0; a < 4; ++a)
            #pragma unroll
            for (int b = 0; b < 4; ++b) pireg[a][b] = 0.f;
        #pragma unroll
        for (int a = 0; a < 16; ++a) pjreg[a] = 0.f;

        for (int c = 0; c < 4; ++c) {     // j-chunks of 64
            f32x4 acc[4][4];
            #pragma unroll
            for (int it = 0; it < 4; ++it)
                #pragma unroll
                for (int jt = 0; jt < 4; ++jt)
                    acc[it][jt] = (f32x4){0.f, 0.f, 0.f, 0.f};
            #pragma unroll
            for (int jt = 0; jt < 4; ++jt) {
                const int row = c * 64 + jt * 16 + sub;
                const int sw  = (row & 7) << 3;
                const short8 b0 = *(const short8*)&sK2[row * 64 + ((g * 8) ^ sw)];
                const short8 b1 = *(const short8*)&sK2[row * 64 + ((32 + g * 8) ^ sw)];
                #pragma unroll
                for (int it = 0; it < 4; ++it) {
                    acc[it][jt] = __builtin_amdgcn_mfma_f32_16x16x32_bf16(afrag[it][0], b0, acc[it][jt], 0, 0, 0);
                    acc[it][jt] = __builtin_amdgcn_mfma_f32_16x16x32_bf16(afrag[it][1], b1, acc[it][jt], 0, 0, 0);
                }
            }
            // epilogue: p = 2^t ; accumulate row (pi) and column (pj) sums
            #pragma unroll
            for (int it = 0; it < 4; ++it)
                #pragma unroll
                for (int jt = 0; jt < 4; ++jt)
                    #pragma unroll
                    for (int r = 0; r < 4; ++r) {
                        const float e = __builtin_amdgcn_exp2f(acc[it][jt][r]);
                        pireg[it][r]    += e;   // i = .. + (l>>4)*4 + r
                        pjreg[c * 4 + jt] += e; // j = (c*4+jt)*16 + (l&15)
                    }
        }

        // pi: reduce across the 16 lanes of each group (distinct j)
        #pragma unroll
        for (int it = 0; it < 4; ++it)
            #pragma unroll
            for (int r = 0; r < 4; ++r) {
                float v = pireg[it][r];
                v += __shfl_xor(v, 1); v += __shfl_xor(v, 2);
                v += __shfl_xor(v, 4); v += __shfl_xor(v, 8);
                if (sub == 0) sPi[qq][w * 64 + it * 16 + g * 4 + r] = v;
            }
        // pj: reduce across the 4 groups (distinct i)
        #pragma unroll
        for (int cj = 0; cj < 16; ++cj) {
            float v = pjreg[cj];
            v += __shfl_xor(v, 16); v += __shfl_xor(v, 32);
            if (l < 16) sTmp[w][cj * 16 + l] = v;
        }
        __syncthreads();
        sPj[qq][tid] = sTmp[0][tid] + sTmp[1][tid] + sTmp[2][tid] + sTmp[3][tid];
        __syncthreads();
    }

    // ---- l[qq] = sum_i pi ----
    {
        const int qq = tid >> 6, lane = tid & 63;
        float ls = sPi[qq][lane] + sPi[qq][64 + lane] + sPi[qq][128 + lane] + sPi[qq][192 + lane];
        ls += __shfl_xor(ls, 1);  ls += __shfl_xor(ls, 2);  ls += __shfl_xor(ls, 4);
        ls += __shfl_xor(ls, 8);  ls += __shfl_xor(ls, 16); ls += __shfl_xor(ls, 32);
        if (lane == 0) sL[qq] = ls;
    }
    // ---- O = pi@V1 + pj@V2 ; each wave covers a 64-row slice ----
    {
        const int gg = tid >> 6, d = tid & 63;
        float a0 = 0.f, a1 = 0.f, a2 = 0.f, a3 = 0.f;
        const float* V1h = v1g + h * (S_ * D_);
        const float* V2h = v2g + h * (S_ * D_);
        for (int i = gg * 64; i < gg * 64 + 64; ++i) {
            const float vv = V1h[i * D_ + d];
            a0 += sPi[0][i] * vv; a1 += sPi[1][i] * vv;
            a2 += sPi[2][i] * vv; a3 += sPi[3][i] * vv;
        }
        for (int j = gg * 64; j < gg * 64 + 64; ++j) {
            const float vv = V2h[j * D_ + d];
            a0 += sPj[0][j] * vv; a1 += sPj[1][j] * vv;
            a2 += sPj[2][j] * vv; a3 += sPj[3][j] * vv;
        }
        sTmp[gg][0 * 64 + d] = a0; sTmp[gg][1 * 64 + d] = a1;
        sTmp[gg][2 * 64 + d] = a2; sTmp[gg][3 * 64 + d] = a3;
    }
    __syncthreads();
    {
        const int qq = tid >> 6, d = tid & 63;
        const float oo = sTmp[0][qq * 64 + d] + sTmp[1][qq * 64 + d]
                       + sTmp[2][qq * 64 + d] + sTmp[3][qq * 64 + d];
        outg[(h * S_ + q0 + qq) * D_ + d] = oo / sL[qq];
        if (tid < QB)
            outg[8 * S_ * D_ + h * S_ + q0 + tid] = logf(sL[tid]);
    }
}

extern "C" void kernel_launch(void* const* d_in, const int* in_sizes, int n_in,
                              void* d_out, int out_size, void* d_ws, size_t ws_size,
                              hipStream_t stream) {
    const float* q  = (const float*)d_in[0];
    const float* k1 = (const float*)d_in[1];
    const float* k2 = (const float*)d_in[2];
    const float* v1 = (const float*)d_in[3];
    const float* v2 = (const float*)d_in[4];
    float* out = (float*)d_out;
    tritt_fused<<<dim3(8 * (S_ / QB)), dim3(256), 0, stream>>>(q, k1, k2, v1, v2, out);
}